// Round 1
// baseline (128.956 us; speedup 1.0000x reference)
//
#include <hip/hip_runtime.h>
#include <math.h>

#define IMG 256
#define NPIX (IMG*IMG)
#define SIGMA_INV 100.0f
#define EPSF 1e-6f
#define LOG2E 1.4426950408889634f
#define TANV 0.5773502691896258f   // tan(30 deg)
#define TSKIP 24.0f
#define NCHUNK 4

__device__ __forceinline__ float fexp2(float x) {
#if __has_builtin(__builtin_amdgcn_exp2f)
  return __builtin_amdgcn_exp2f(x);
#else
  return exp2f(x);
#endif
}
__device__ __forceinline__ float frcp(float x) {
#if __has_builtin(__builtin_amdgcn_rcpf)
  return __builtin_amdgcn_rcpf(x);
#else
  return 1.0f / x;
#endif
}

// Kernel 1: look_at transform + perspective projection of all vertices.
__global__ void proj_kernel(const float* __restrict__ verts,
                            const float* __restrict__ cam,
                            float* __restrict__ proj, int V) {
  int v = blockIdx.x * blockDim.x + threadIdx.x;
  if (v >= V) return;
  float ex = cam[0], ey = cam[1], ez = cam[2];
  // z = (0 - eye) / (||eye|| + eps)
  float zn = sqrtf(ex * ex + ey * ey + ez * ez) + EPSF;
  float zx = -ex / zn, zy = -ey / zn, zz = -ez / zn;
  // x = cross(up=(0,1,0), z) = (zz, 0, -zx), normalized
  float xn = sqrtf(zz * zz + zx * zx) + EPSF;
  float xx = zz / xn, xy = 0.0f, xz = -zx / xn;
  // y = cross(z, x)
  float yx = zy * xz - zz * xy;
  float yy = zz * xx - zx * xz;
  float yz = zx * xy - zy * xx;
  float px = verts[3 * v + 0] - ex;
  float py = verts[3 * v + 1] - ey;
  float pz = verts[3 * v + 2] - ez;
  float vx = px * xx + py * xy + pz * xz;
  float vy = px * yx + py * yy + pz * yz;
  float vz = px * zx + py * zy + pz * zz;
  float zw = vz * TANV;
  proj[2 * v + 0] = vx / zw;
  proj[2 * v + 1] = vy / zw;
}

// Kernel 2: per-face edge constants.
// t_k(p) = px*A.x + py*A.y + A.z, where sigmoid arg z_k = d_k*s/sigma and
// t_k = -z_k*log2(e) so sigmoid = 1/(1+exp2(t_k)).
__global__ void face_kernel(const int* __restrict__ faces,
                            const float* __restrict__ proj,
                            float4* __restrict__ fd, int F) {
  int f = blockIdx.x * blockDim.x + threadIdx.x;
  if (f >= F) return;
  int i0 = faces[3 * f + 0], i1 = faces[3 * f + 1], i2 = faces[3 * f + 2];
  float ax = proj[2 * i0], ay = proj[2 * i0 + 1];
  float bx = proj[2 * i1], by = proj[2 * i1 + 1];
  float cx = proj[2 * i2], cy = proj[2 * i2 + 1];
  float e01x = bx - ax, e01y = by - ay;
  float e02x = cx - ax, e02y = cy - ay;
  float area = e01x * e02y - e01y * e02x;
  float s = (area > 0.0f) ? 1.0f : ((area < 0.0f) ? -1.0f : 0.0f);
  float K = -s * SIGMA_INV * LOG2E;
  float axs[3] = {ax, bx, cx}, ays[3] = {ay, by, cy};
  float bxs[3] = {bx, cx, ax}, bys[3] = {by, cy, ay};
#pragma unroll
  for (int k = 0; k < 3; ++k) {
    float ex = bxs[k] - axs[k], ey = bys[k] - ays[k];
    float ln = sqrtf(ex * ex + ey * ey) + EPSF;
    float nx = -ey / ln, ny = ex / ln;
    float c = axs[k] * nx + ays[k] * ny;
    fd[f * 3 + k] = make_float4(nx * K, ny * K, -c * K, 0.0f);
  }
}

// Kernel 3: per-pixel partial product over one face chunk.
// Wave = 8x8 pixel tile; block (4 waves) = 16x16 tile; gridDim.x = 256 tiles,
// gridDim.y = face chunk. Faces read with a uniform index -> scalar loads.
__global__ __launch_bounds__(256) void sil_kernel(const float4* __restrict__ fd,
                                                  float* __restrict__ part,
                                                  int fpc, int F) {
  int tid = threadIdx.x;
  int lane = tid & 63, wave = tid >> 6;
  int bx = blockIdx.x;
  int ix = ((bx & 15) << 4) + ((wave & 1) << 3) + (lane & 7);
  int iy = ((bx >> 4) << 4) + ((wave >> 1) << 3) + (lane >> 3);
  float px = (float)ix * (2.0f / IMG) + (1.0f / IMG - 1.0f);
  float py = 1.0f - (2.0f * (float)iy + 1.0f) * (1.0f / IMG);

  int f0 = blockIdx.y * fpc;
  int f1 = f0 + fpc; if (f1 > F) f1 = F;

  float acc = 1.0f;
  for (int f = f0; f < f1; ++f) {
    float4 a0 = fd[3 * f + 0];
    float4 a1 = fd[3 * f + 1];
    float4 a2 = fd[3 * f + 2];
    float t0 = fmaf(px, a0.x, fmaf(py, a0.y, a0.z));
    float t1 = fmaf(px, a1.x, fmaf(py, a1.y, a1.z));
    float t2 = fmaf(px, a2.x, fmaf(py, a2.y, a2.z));
    float tmax = fmaxf(t0, fmaxf(t1, t2));
    // If every lane has some sigmoid factor <= 2^-24, frag ~ 0: skip.
    if (__ballot(tmax < TSKIP)) {
      float D = (1.0f + fexp2(t0)) * (1.0f + fexp2(t1)) * (1.0f + fexp2(t2));
      acc *= 1.0f - frcp(D);  // frag = 1/D
    }
  }
  part[blockIdx.y * NPIX + iy * IMG + ix] = acc;
}

// Kernel 4: combine chunks, squared error vs image_ref, reduce to scalar.
__global__ __launch_bounds__(256) void loss_kernel(const float* __restrict__ part,
                                                   const float* __restrict__ ref,
                                                   float* __restrict__ out) {
  int p = blockIdx.x * 256 + threadIdx.x;
  float a = part[p] * part[p + NPIX] * part[p + 2 * NPIX] * part[p + 3 * NPIX];
  float sil = 1.0f - a;
  float d = sil - ref[p];
  float v = d * d;
#pragma unroll
  for (int off = 32; off > 0; off >>= 1) v += __shfl_down(v, off);
  __shared__ float red[4];
  if ((threadIdx.x & 63) == 0) red[threadIdx.x >> 6] = v;
  __syncthreads();
  if (threadIdx.x == 0) atomicAdd(out, red[0] + red[1] + red[2] + red[3]);
}

extern "C" void kernel_launch(void* const* d_in, const int* in_sizes, int n_in,
                              void* d_out, int out_size, void* d_ws, size_t ws_size,
                              hipStream_t stream) {
  const float* verts = (const float*)d_in[0];
  const int* faces = (const int*)d_in[1];
  const float* cam = (const float*)d_in[2];
  const float* imref = (const float*)d_in[3];
  int V = in_sizes[0] / 3;  // 502
  int F = in_sizes[1] / 3;  // 1000

  char* ws = (char*)d_ws;
  float* proj = (float*)ws;                 // V*2 floats   (< 4 KB)
  float4* fd = (float4*)(ws + 4096);        // F*3 float4   (48 KB)
  float* part = (float*)(ws + 65536);       // NCHUNK*NPIX floats (1 MB)
  float* out = (float*)d_out;

  hipMemsetAsync(out, 0, sizeof(float), stream);
  proj_kernel<<<(V + 255) / 256, 256, 0, stream>>>(verts, cam, proj, V);
  face_kernel<<<(F + 255) / 256, 256, 0, stream>>>(faces, proj, fd, F);
  int fpc = (F + NCHUNK - 1) / NCHUNK;
  dim3 grid(256, NCHUNK);
  sil_kernel<<<grid, 256, 0, stream>>>(fd, part, fpc, F);
  loss_kernel<<<NPIX / 256, 256, 0, stream>>>(part, imref, out);
}